// Round 8
// baseline (424.828 us; speedup 1.0000x reference)
//
#include <hip/hip_runtime.h>

#define KHOPS  8
#define BS     1024
#define GRID   256             // 1 block/CU (147 KB LDS forces it) — all co-resident
#define MAXL   50176
#define HWORDS (MAXL / 2)      // 25088 u32 = 100 KB histogram (u16-pair counters)
#define P1     8               // merge groups
#define RPQ    (GRID / P1)     // replicas per merge group = 32
#define TSCALE 2048.0f         // traffic fixed-point scale (Q11)
#define XSCALE 131072.0f       // X_l fixed-point scale (Q17; X < 0.5 guaranteed)
#define POISON 0xAAAAAAAAu

typedef unsigned char  u8;
typedef unsigned short u16;
typedef unsigned int   u32;

// ---------------------------------------------------------------------------
// grid barrier: monotonic counter in ws. ws is poisoned 0xAA each launch; the
// first block to touch the counter CAS-converts poison->0 (max legit value is
// 9*256=2304, so poison is unambiguous). __threadfence() = agent-scope fence
// (L2 writeback + invalidate) for cross-XCD visibility.
// ---------------------------------------------------------------------------
__device__ __forceinline__ void gbar(u32* cnt, u32 target) {
    __syncthreads();                       // drains vmcnt: block's stores in L2
    if (threadIdx.x == 0) {
        __threadfence();                   // release: push L2 to memory
        __hip_atomic_fetch_add(cnt, 1u, __ATOMIC_RELAXED, __HIP_MEMORY_SCOPE_AGENT);
        while (__hip_atomic_load(cnt, __ATOMIC_RELAXED, __HIP_MEMORY_SCOPE_AGENT) < target)
            __builtin_amdgcn_s_sleep(2);
        __threadfence();                   // acquire: invalidate stale L1/L2
    }
    __syncthreads();
}

// ---------------------------------------------------------------------------
// mega kernel: convert + 3x(scatter/merge/link-update) + epilogue + gather,
// path data persistent in registers (4 paths/thread, loaded once).
// ---------------------------------------------------------------------------
__global__ __launch_bounds__(BS) void mega_kernel(
        const float* __restrict__ P,         // (n_paths,3)
        const float* __restrict__ Lcap,      // (n_links,1)
        const int*   __restrict__ pl_edges,  // (KHOPS,n_paths)
        u32* __restrict__ cnt,
        u32* __restrict__ partial,           // [P1][n_links] u32
        u32* __restrict__ Trep,              // [GRID][nwords] u32
        u8*  __restrict__ bpq,               // (n_links) Q8
        u16* __restrict__ xq,                // (n_links) Q17
        float* __restrict__ res,             // (n_paths)
        float* __restrict__ out_links,       // (n_links,3)
        int n_paths, int n_links, int nwords) {
    __shared__ u8  bpl[MAXL];                // 50176 B
    __shared__ u32 h[HWORDS];                // 100352 B (total 147 KiB)
    const int tid = threadIdx.x;
    const int bid = blockIdx.x;
    const int gt  = bid * BS + tid;

    if (tid == 0) {                          // barrier counter: poison -> 0
        u32 expected = POISON;
        __hip_atomic_compare_exchange_strong(cnt, &expected, 0u,
            __ATOMIC_ACQ_REL, __ATOMIC_RELAXED, __HIP_MEMORY_SCOPE_AGENT);
    }

    // ---- load path data into persistent registers (once) ----
    const int p0 = gt * 4;                   // n_paths % 4 == 0
    const bool act = (p0 < n_paths);
    u32 ep[KHOPS][2];                        // packed u16 link pairs
    float a0 = 0, a1 = 0, a2 = 0, a3 = 0;
    if (act) {
#pragma unroll
        for (int k = 0; k < KHOPS; ++k) {
            int4 e4 = *(const int4*)&pl_edges[k * n_paths + p0];  // coalesced
            ep[k][0] = (u32)(e4.x - n_paths) | ((u32)(e4.y - n_paths) << 16);
            ep[k][1] = (u32)(e4.z - n_paths) | ((u32)(e4.w - n_paths) << 16);
        }
        a0 = P[3 * p0 + 1]; a1 = P[3 * p0 + 4];
        a2 = P[3 * p0 + 7]; a3 = P[3 * p0 + 10];
    }

    u32 bar = 0;
    const int mq = bid >> 5;                 // merge group 0..7
    const int mw = (bid & 31) * BS + tid;    // merge word index

    for (int it = 0; it < 3; ++it) {
        // ---- bp table to LDS (iter 0: bp == 0.5 constant, no table) ----
        if (it > 0)
            for (int i = tid; i < n_links; i += BS) bpl[i] = bpq[i];
        for (int i = tid; i < HWORDS; i += BS) h[i] = 0u;
        __syncthreads();

        // ---- deposits (LDS atomics, register-resident paths) ----
        if (act) {
            float t0 = a0, t1 = a1, t2 = a2, t3 = a3;
#pragma unroll
            for (int k = 0; k < KHOPS; ++k) {
                u32 l0 = ep[k][0] & 0xffffu, l1 = ep[k][0] >> 16;
                u32 l2 = ep[k][1] & 0xffffu, l3 = ep[k][1] >> 16;
                atomicAdd(&h[l0 >> 1], __float2uint_rn(t0 * TSCALE) << ((l0 & 1) << 4));
                atomicAdd(&h[l1 >> 1], __float2uint_rn(t1 * TSCALE) << ((l1 & 1) << 4));
                atomicAdd(&h[l2 >> 1], __float2uint_rn(t2 * TSCALE) << ((l2 & 1) << 4));
                atomicAdd(&h[l3 >> 1], __float2uint_rn(t3 * TSCALE) << ((l3 & 1) << 4));
                if (it == 0) {
                    t0 *= 0.5f; t1 *= 0.5f; t2 *= 0.5f; t3 *= 0.5f;
                } else {
                    t0 *= (float)(256 - (int)bpl[l0]) * (1.0f / 256.0f);
                    t1 *= (float)(256 - (int)bpl[l1]) * (1.0f / 256.0f);
                    t2 *= (float)(256 - (int)bpl[l2]) * (1.0f / 256.0f);
                    t3 *= (float)(256 - (int)bpl[l3]) * (1.0f / 256.0f);
                }
            }
        }
        __syncthreads();

        // ---- flush histogram to private replica slice ----
        {
            u32* Tm = Trep + (size_t)bid * nwords;
            for (int i = tid; i < nwords; i += BS) Tm[i] = h[i];
        }
        gbar(cnt, (++bar) * GRID);

        // ---- merge stage A: 32 replicas per group, coalesced in word ----
        if (mw < nwords) {
            u32 slo = 0, shi = 0;
#pragma unroll 4
            for (int j = 0; j < RPQ; ++j) {
                u32 v = Trep[(size_t)(mq * RPQ + j) * nwords + mw];
                slo += v & 0xffffu;
                shi += v >> 16;
            }
            *(uint2*)&partial[(size_t)mq * n_links + 2 * mw] = make_uint2(slo, shi);
        }
        gbar(cnt, (++bar) * GRID);

        // ---- stage B: link update (+ fused epilogue on last iteration) ----
        if (gt < n_links) {
            u32 s = 0;
#pragma unroll
            for (int q = 0; q < P1; ++q)
                s += partial[(size_t)q * n_links + gt];
            float T   = (float)s * (1.0f / TSCALE);
            float cap = Lcap[gt] * (1.0f / 1000.0f);
            float rho = T / cap;
            float r2 = rho * rho, r4 = r2 * r2, r8 = r4 * r4, r16 = r8 * r8;
            float r32 = r16 * r16, r33 = r32 * rho;
            if (it < 2) {
                float bp = (1.0f - rho) * r32 / (1.0f - r33 + 1e-8f);
                u32 b = __float2uint_rn(bp * 256.0f);
                bpq[gt] = (u8)(b > 255u ? 255u : b);
            } else {
                float pi0 = (1.0f - rho) / (1.0f - r33);   // no epsilon (ref)
                float S = 1.0f, rp = 1.0f;
#pragma unroll
                for (int m = 1; m <= 32; ++m) { rp *= rho; S += (float)m * rp; }
                float Lq = pi0 * S * (1.0f / 32.0f);
                float X  = Lq * 32000.0f / Lcap[gt];
                u32 xf = __float2uint_rn(X * XSCALE);
                xq[gt] = (u16)(xf > 65535u ? 65535u : xf);
                out_links[3 * gt + 0] = Lq;
                out_links[3 * gt + 1] = rho;
                out_links[3 * gt + 2] = pi0 * r32;
            }
        }
        gbar(cnt, (++bar) * GRID);
    }

    // ---- gather: X_l table in LDS (reuse h), register-resident edges ----
    u16* xl = (u16*)h;
    for (int i = tid; i < n_links; i += BS) xl[i] = xq[i];
    __syncthreads();
    if (act) {
        u32 s0 = 0, s1 = 0, s2 = 0, s3 = 0;
#pragma unroll
        for (int k = 0; k < KHOPS; ++k) {
            s0 += xl[ep[k][0] & 0xffffu];
            s1 += xl[ep[k][0] >> 16];
            s2 += xl[ep[k][1] & 0xffffu];
            s3 += xl[ep[k][1] >> 16];
        }
        *(float4*)&res[p0] = make_float4((float)s0 * (1.0f / XSCALE),
                                         (float)s1 * (1.0f / XSCALE),
                                         (float)s2 * (1.0f / XSCALE),
                                         (float)s3 * (1.0f / XSCALE));
    }
}

// ---------------------------------------------------------------------------
extern "C" void kernel_launch(void* const* d_in, const int* in_sizes, int n_in,
                              void* d_out, int out_size, void* d_ws, size_t ws_size,
                              hipStream_t stream) {
    const float* P        = (const float*)d_in[0];   // (n_paths, 3)
    const float* Lcap     = (const float*)d_in[1];   // (n_links, 1)
    const int*   pl_edges = (const int*)d_in[3];     // (KHOPS, n_paths)

    const int n_paths = in_sizes[0] / 3;
    const int n_links = in_sizes[1];
    const int nwords  = (n_links + 1) / 2;

    // ws layout: cnt (256 B) | partial u32[P1*nl] | Trep u32[GRID*nwords]
    //            | bpq u8[nl] | xq u16[nl]                      (~27.5 MB)
    char* w = (char*)d_ws;
    u32* cnt     = (u32*)w;                   w += 256;
    u32* partial = (u32*)w;                   w += (size_t)P1 * n_links * 4;
    u32* Trep    = (u32*)w;                   w += (size_t)GRID * nwords * 4;
    u8*  bpq     = (u8*)w;                    w += (size_t)n_links;
    w = (char*)(((size_t)w + 15) & ~15ull);
    u16* xq      = (u16*)w;

    float* res       = (float*)d_out;                // (n_paths,)
    float* out_links = res + n_paths;                // (n_links, 3)

    mega_kernel<<<GRID, BS, 0, stream>>>(P, Lcap, pl_edges, cnt, partial, Trep,
                                         bpq, xq, res, out_links,
                                         n_paths, n_links, nwords);
}

// Round 9
// 174.059 us; speedup vs baseline: 2.4407x; 2.4407x over previous
//
#include <hip/hip_runtime.h>

#define KHOPS  8
#define BS     1024            // scatter/gather/merge block size
#define MAXL   50176           // max links (LDS tables sized for this)
#define HWORDS (MAXL / 2)      // 25088 u32 words = 100352 B (u16-pair histogram)
#define GRID   256             // scatter grid: 1 block/CU
#define NXCD   8               // merge groups == XCD count
#define RPQ    (GRID / NXCD)   // replicas per merge group = 32
#define TSCALE  2048.0f        // traffic deposit fixed-point scale (Q11)
#define XSCALE  131072.0f      // X_l fixed-point scale (Q17; X < 0.5 guaranteed)

typedef unsigned char  u8;
typedef unsigned short u16;
typedef unsigned int   u32;

// ---------------------------------------------------------------------------
// deposit helper: packed u16-pair histogram, ds_add_u32
// ---------------------------------------------------------------------------
__device__ __forceinline__ void deposit(u32* h, u32 link, float t) {
    atomicAdd(&h[link >> 1], __float2uint_rn(t * TSCALE) << ((link & 1) << 4));
}

// ---------------------------------------------------------------------------
// scatter, iteration 1 (fused convert): reads raw int edges + P, converts to
// packed u16 (writes e16 for later passes) and compact A; bp == 0.5 constant.
// Single full-size histogram (100 KB LDS), 4 paths/thread.
// ---------------------------------------------------------------------------
__global__ __launch_bounds__(BS) void scatter_first(
        const float* __restrict__ P,         // (n_paths,3)
        const int*   __restrict__ pl_edges,  // (KHOPS,n_paths)
        u16*   __restrict__ e16,             // out: packed link ids
        float* __restrict__ A,               // out: compact traffic source
        u32*   __restrict__ Trep,            // [GRID][nwords]
        int n_paths, int nwords) {
    __shared__ u32 h[HWORDS];
    const int tid = threadIdx.x;
    const int nthreads = gridDim.x * BS;

    for (int i = tid; i < HWORDS; i += BS) h[i] = 0u;
    __syncthreads();

    for (int p = (blockIdx.x * BS + tid) * 4; p < n_paths; p += 4 * nthreads) {
        uint2 ep[KHOPS];
#pragma unroll
        for (int k = 0; k < KHOPS; ++k) {
            int4 e4 = *(const int4*)&pl_edges[k * n_paths + p];   // coalesced
            ep[k].x = (u32)(e4.x - n_paths) | ((u32)(e4.y - n_paths) << 16);
            ep[k].y = (u32)(e4.z - n_paths) | ((u32)(e4.w - n_paths) << 16);
            *(uint2*)&e16[k * n_paths + p] = ep[k];               // coalesced
        }
        float4 q0 = *(const float4*)&P[3 * p];       // A = P[:,1]
        float4 q1 = *(const float4*)&P[3 * p + 4];
        float4 q2 = *(const float4*)&P[3 * p + 8];
        float t0 = q0.y, t1 = q1.x, t2 = q1.w, t3 = q2.z;
        *(float4*)&A[p] = make_float4(t0, t1, t2, t3);
#pragma unroll
        for (int k = 0; k < KHOPS; ++k) {
            deposit(h, ep[k].x & 0xffffu, t0);
            deposit(h, ep[k].x >> 16,     t1);
            deposit(h, ep[k].y & 0xffffu, t2);
            deposit(h, ep[k].y >> 16,     t3);
            t0 *= 0.5f; t1 *= 0.5f; t2 *= 0.5f; t3 *= 0.5f;
        }
    }
    __syncthreads();

    u32* Tmine = Trep + (size_t)blockIdx.x * nwords;
    for (int i = tid; i < nwords; i += BS) Tmine[i] = h[i];
}

// ---------------------------------------------------------------------------
// scatter, iterations 2+: bp table in LDS as u8 Q8 (50 KB) + full histogram
// (100 KB) = 147 KB -> single chunk, 1 block/CU.
// ---------------------------------------------------------------------------
__global__ __launch_bounds__(BS) void scatter_rest(
        const float* __restrict__ A,
        const u16*   __restrict__ e16,
        const u8*    __restrict__ bpq,       // (n_links) Q8
        u32*         __restrict__ Trep,
        int n_paths, int n_links, int nwords) {
    __shared__ u8  bpl[MAXL];                // 50176 B
    __shared__ u32 h[HWORDS];                // 100352 B
    const int tid = threadIdx.x;
    const int nthreads = gridDim.x * BS;

    for (int i = tid; i < n_links; i += BS) bpl[i] = bpq[i];
    for (int i = tid; i < HWORDS; i += BS) h[i] = 0u;
    __syncthreads();

    for (int p = (blockIdx.x * BS + tid) * 4; p < n_paths; p += 4 * nthreads) {
        uint2 ep[KHOPS];
#pragma unroll
        for (int k = 0; k < KHOPS; ++k)
            ep[k] = *(const uint2*)&e16[k * n_paths + p];
        float4 a = *(const float4*)&A[p];
        float t0 = a.x, t1 = a.y, t2 = a.z, t3 = a.w;
#pragma unroll
        for (int k = 0; k < KHOPS; ++k) {
            u32 l0 = ep[k].x & 0xffffu, l1 = ep[k].x >> 16;
            u32 l2 = ep[k].y & 0xffffu, l3 = ep[k].y >> 16;
            deposit(h, l0, t0);
            deposit(h, l1, t1);
            deposit(h, l2, t2);
            deposit(h, l3, t3);
            t0 *= (float)(256 - (int)bpl[l0]) * (1.0f / 256.0f);
            t1 *= (float)(256 - (int)bpl[l1]) * (1.0f / 256.0f);
            t2 *= (float)(256 - (int)bpl[l2]) * (1.0f / 256.0f);
            t3 *= (float)(256 - (int)bpl[l3]) * (1.0f / 256.0f);
        }
    }
    __syncthreads();

    u32* Tmine = Trep + (size_t)blockIdx.x * nwords;
    for (int i = tid; i < nwords; i += BS) Tmine[i] = h[i];
}

// ---------------------------------------------------------------------------
// merge: group q sums replicas r == q (mod 8). Replica r was written by
// scatter block r, which sits on XCD r%8 (round-robin dispatch heuristic);
// merge block blockIdx.x has q = blockIdx.x & 7 -> same XCD -> L2-local reads.
// ---------------------------------------------------------------------------
__global__ __launch_bounds__(BS) void merge_kernel(
        const u32* __restrict__ Trep,
        u32* __restrict__ partial,           // [NXCD][n_links]
        int n_links, int nwords) {
    const int q = blockIdx.x & (NXCD - 1);
    const int w = (blockIdx.x >> 3) * BS + threadIdx.x;
    if (w >= nwords) return;
    u32 slo = 0, shi = 0;
#pragma unroll 4
    for (int j = 0; j < RPQ; ++j) {
        u32 v = Trep[(size_t)(q + NXCD * j) * nwords + w];
        slo += v & 0xffffu;
        shi += v >> 16;
    }
    *(uint2*)&partial[(size_t)q * n_links + 2 * w] = make_uint2(slo, shi);
}

// ---------------------------------------------------------------------------
// link update: T = (sum of 8 integer partials)/TSCALE; rho; writes bp (Q8)
// on early iterations, full epilogue (outputs + xq) on the last.
// ---------------------------------------------------------------------------
__global__ void link_update_kernel(const float* __restrict__ L,
                                   const u32*   __restrict__ partial,
                                   u8*          __restrict__ bpq,
                                   u16*         __restrict__ xq,
                                   float*       __restrict__ out_links,
                                   int n_links, int last) {
    int l = blockIdx.x * blockDim.x + threadIdx.x;
    if (l >= n_links) return;
    u32 s = 0;
#pragma unroll
    for (int q = 0; q < NXCD; ++q)
        s += partial[(size_t)q * n_links + l];
    float T   = (float)s * (1.0f / TSCALE);
    float cap = L[l] * (1.0f / 1000.0f);
    float rho = T / cap;
    float r2 = rho * rho, r4 = r2 * r2, r8 = r4 * r4, r16 = r8 * r8;
    float r32 = r16 * r16, r33 = r32 * rho;
    if (!last) {
        float bp = (1.0f - rho) * r32 / (1.0f - r33 + 1e-8f);
        u32 b = __float2uint_rn(bp * 256.0f);
        bpq[l] = (u8)(b > 255u ? 255u : b);
    } else {
        float pi0 = (1.0f - rho) / (1.0f - r33);     // no epsilon (ref)
        float S = 1.0f, rp = 1.0f;
#pragma unroll
        for (int m = 1; m <= 32; ++m) { rp *= rho; S += (float)m * rp; }
        float Lq = pi0 * S * (1.0f / 32.0f);
        float X  = Lq * 32000.0f / L[l];
        u32 xf = __float2uint_rn(X * XSCALE);
        xq[l] = (u16)(xf > 65535u ? 65535u : xf);
        out_links[3 * l + 0] = Lq;
        out_links[3 * l + 1] = rho;
        out_links[3 * l + 2] = pi0 * r32;
    }
}

// ---------------------------------------------------------------------------
// gather: X_l table in LDS (Q17 u16); integer per-path sum, 4 paths/thread.
// ---------------------------------------------------------------------------
__global__ __launch_bounds__(BS) void gather_kernel(
        const u16* __restrict__ e16,
        const u16* __restrict__ xq,
        float*     __restrict__ res,
        int n_paths, int n_links) {
    __shared__ u16 xl[MAXL];
    const int tid = threadIdx.x;
    for (int i = tid; i < n_links; i += BS) xl[i] = xq[i];
    __syncthreads();

    const int nthreads = gridDim.x * BS;
    for (int p = (blockIdx.x * BS + tid) * 4; p < n_paths; p += 4 * nthreads) {
        u32 s0 = 0, s1 = 0, s2 = 0, s3 = 0;
#pragma unroll
        for (int k = 0; k < KHOPS; ++k) {
            uint2 ep = *(const uint2*)&e16[k * n_paths + p];
            s0 += xl[ep.x & 0xffffu];
            s1 += xl[ep.x >> 16];
            s2 += xl[ep.y & 0xffffu];
            s3 += xl[ep.y >> 16];
        }
        *(float4*)&res[p] = make_float4((float)s0 * (1.0f / XSCALE),
                                        (float)s1 * (1.0f / XSCALE),
                                        (float)s2 * (1.0f / XSCALE),
                                        (float)s3 * (1.0f / XSCALE));
    }
}

// ---------------------------------------------------------------------------
extern "C" void kernel_launch(void* const* d_in, const int* in_sizes, int n_in,
                              void* d_out, int out_size, void* d_ws, size_t ws_size,
                              hipStream_t stream) {
    const float* P        = (const float*)d_in[0];   // (n_paths, 3)
    const float* L        = (const float*)d_in[1];   // (n_links, 1)
    const int*   pl_edges = (const int*)d_in[3];     // (KHOPS, n_paths)

    const int n_paths = in_sizes[0] / 3;
    const int n_links = in_sizes[1];
    const int n_edges = KHOPS * n_paths;
    const int nwords  = (n_links + 1) / 2;

    // ws layout: e16 | A | bpq(u8) | xq(u16) | partial (u32 NXCD*nl) | Trep
    char* w = (char*)d_ws;
    u16*   e16 = (u16*)w;                     w += (size_t)n_edges * 2;
    w = (char*)(((size_t)w + 15) & ~15ull);
    float* A   = (float*)w;                   w += (size_t)n_paths * 4;
    u8*    bpq = (u8*)w;                      w += (size_t)n_links;
    w = (char*)(((size_t)w + 15) & ~15ull);
    u16*   xq  = (u16*)w;                     w += (size_t)n_links * 2;
    w = (char*)(((size_t)w + 15) & ~15ull);
    u32* partial = (u32*)w;                   w += (size_t)NXCD * n_links * 4;
    u32* Trep    = (u32*)w;                   // GRID*nwords*4 = 25.6 MB

    float* res       = (float*)d_out;                // (n_paths,)
    float* out_links = res + n_paths;                // (n_links, 3)

    const int bs = 256;
    const int gl = (n_links + bs - 1) / bs;
    const int gm = NXCD * ((nwords + BS - 1) / BS);  // XCD-aligned merge grid

    for (int it = 0; it < 3; ++it) {
        if (it == 0)
            scatter_first<<<GRID, BS, 0, stream>>>(P, pl_edges, e16, A, Trep,
                                                   n_paths, nwords);
        else
            scatter_rest<<<GRID, BS, 0, stream>>>(A, e16, bpq, Trep,
                                                  n_paths, n_links, nwords);
        merge_kernel<<<gm, BS, 0, stream>>>(Trep, partial, n_links, nwords);
        link_update_kernel<<<gl, bs, 0, stream>>>(L, partial, bpq, xq,
                                                  out_links, n_links,
                                                  it == 2 ? 1 : 0);
    }
    gather_kernel<<<GRID, BS, 0, stream>>>(e16, xq, res, n_paths, n_links);
}